// Round 3
// baseline (2733.715 us; speedup 1.0000x reference)
//
#include <hip/hip_runtime.h>
#include <cmath>

#define TT    2048
#define HH    128
#define NDIN  3
#define NDOUT 26
#define NTHR  512

typedef _Float16 f16x8 __attribute__((ext_vector_type(8)));
typedef float    f32x4 __attribute__((ext_vector_type(4)));

__device__ __forceinline__ float fast_rcp(float x){ return __builtin_amdgcn_rcpf(x); }

__device__ __forceinline__ f16x8 cvt8(const float* __restrict__ p){
    float4 a = *(const float4*)p;
    float4 b = *(const float4*)(p+4);
    f16x8 r;
    r[0]=(_Float16)a.x; r[1]=(_Float16)a.y; r[2]=(_Float16)a.z; r[3]=(_Float16)a.w;
    r[4]=(_Float16)b.x; r[5]=(_Float16)b.y; r[6]=(_Float16)b.z; r[7]=(_Float16)b.w;
    return r;
}

__global__
__attribute__((amdgpu_flat_work_group_size(NTHR, NTHR), amdgpu_waves_per_eu(2, 2)))
void slstm2_mfma(
    const float* __restrict__ x,
    const float* __restrict__ W0, const float* __restrict__ R0, const float* __restrict__ b0,
    const float* __restrict__ W1, const float* __restrict__ R1, const float* __restrict__ b1,
    const float* __restrict__ Wmu, const float* __restrict__ bmu,
    const float* __restrict__ Wsig, const float* __restrict__ bsig,
    float* __restrict__ out, int B)
{
    const int b    = blockIdx.x;
    const int tid  = threadIdx.x;
    const int wave = tid >> 6;
    const int lane = tid & 63;
    const int m    = lane & 15;    // row-in-tile (0..15)
    const int g    = lane >> 4;    // k-group (0..3)

    __shared__ float xs[TT * NDIN];                      // 24 KB
    __shared__ __align__(16) _Float16 hcat[2 * HH];      // [h1 | h2] f16
    __shared__ __align__(16) float g1q[HH * 4];          // layer1 gate quads, elem-major
    __shared__ __align__(16) float g2q[HH * 4];          // layer2 gate quads
    __shared__ __align__(16) float w0g[4][HH * 4];       // [gate][elem*4 + {w0,w1,w2,b0}]
    __shared__ __align__(16) float b1qs[HH * 4];         // [elem*4 + gate]
    __shared__ float h2f[HH];

    // ---- stage x[b] (coalesced) ----
    const float* xb = x + (size_t)b * (TT * NDIN);
    #pragma unroll
    for (int r = 0; r < (TT * NDIN) / NTHR; ++r)
        xs[r * NTHR + tid] = xb[r * NTHR + tid];

    // ---- stage packed W0/b0 (per-element gate quads) and b1 quads ----
    if (tid < HH) {
        #pragma unroll
        for (int q = 0; q < 4; ++q) {
            w0g[q][tid*4+0] = W0[(q*HH + tid)*NDIN + 0];
            w0g[q][tid*4+1] = W0[(q*HH + tid)*NDIN + 1];
            w0g[q][tid*4+2] = W0[(q*HH + tid)*NDIN + 2];
            w0g[q][tid*4+3] = b0[q*HH + tid];
            b1qs[tid*4+q]   = b1[q*HH + tid];
        }
        hcat[tid] = (_Float16)0.f;
        hcat[HH + tid] = (_Float16)0.f;
    }

    // ---- load A fragments (gate-interleaved rows), f16, registers ----
    // Tile tau = wave*4+tl covers elems 4tau..4tau+3; row-in-tile m = 4*(elem-4tau)+gate.
    f16x8 a1[4][4];   // L1: R0 (K=128)
    f16x8 a2[4][8];   // L2: [W1 | R1] (K=256)
    #pragma unroll
    for (int tl = 0; tl < 4; ++tl) {
        const int e = (wave*4 + tl)*4 + (m >> 2);
        const int q = m & 3;
        const size_t row = (size_t)(q*HH + e);
        #pragma unroll
        for (int kt = 0; kt < 4; ++kt)
            a1[tl][kt] = cvt8(R0 + row*HH + kt*32 + g*8);
        #pragma unroll
        for (int kt = 0; kt < 4; ++kt)
            a2[tl][kt] = cvt8(W1 + row*HH + kt*32 + g*8);
        #pragma unroll
        for (int kt = 0; kt < 4; ++kt)
            a2[tl][4+kt] = cvt8(R1 + row*HH + kt*32 + g*8);
    }

    float c_s = 0.f, n_s = 0.f, m_s = 0.f, hlast = 0.f;
    __syncthreads();

    // Pipelined: iter t computes L1 preacts for step t (from h1[t-1]) and
    // L2 preacts for step t-1 (from h1[t-1] and h2[t-2], concatenated in hcat).
    for (int t = 0; t <= TT; ++t) {
        f16x8 bf[4];
        #pragma unroll
        for (int kt = 0; kt < 4; ++kt)
            bf[kt] = *(const f16x8*)(hcat + kt*32 + g*8);      // h1 chunks (16-way bcast)

        f32x4 cL1[4];
        #pragma unroll
        for (int tl = 0; tl < 4; ++tl) cL1[tl] = f32x4{0.f,0.f,0.f,0.f};
        #pragma unroll
        for (int kt = 0; kt < 4; ++kt) {
            #pragma unroll
            for (int tl = 0; tl < 4; ++tl)
                cL1[tl] = __builtin_amdgcn_mfma_f32_16x16x32_f16(a1[tl][kt], bf[kt], cL1[tl], 0, 0, 0);
        }
        if (m == 0) {   // lanes 0,16,32,48: each holds a full gate quad in 4 regs
            #pragma unroll
            for (int tl = 0; tl < 4; ++tl) {
                const int e = (wave*4 + tl)*4 + g;
                *(f32x4*)(g1q + e*4) = cL1[tl];
            }
        }

        f32x4 cL2[4];
        #pragma unroll
        for (int tl = 0; tl < 4; ++tl) cL2[tl] = f32x4{0.f,0.f,0.f,0.f};
        #pragma unroll
        for (int kt = 0; kt < 4; ++kt) {     // W1 * h1 part
            #pragma unroll
            for (int tl = 0; tl < 4; ++tl)
                cL2[tl] = __builtin_amdgcn_mfma_f32_16x16x32_f16(a2[tl][kt], bf[kt], cL2[tl], 0, 0, 0);
        }
        #pragma unroll
        for (int kt = 0; kt < 4; ++kt)
            bf[kt] = *(const f16x8*)(hcat + HH + kt*32 + g*8);  // h2 chunks
        #pragma unroll
        for (int kt = 0; kt < 4; ++kt) {     // R1 * h2 part
            #pragma unroll
            for (int tl = 0; tl < 4; ++tl)
                cL2[tl] = __builtin_amdgcn_mfma_f32_16x16x32_f16(a2[tl][4+kt], bf[kt], cL2[tl], 0, 0, 0);
        }
        if (m == 0) {
            #pragma unroll
            for (int tl = 0; tl < 4; ++tl) {
                const int e = (wave*4 + tl)*4 + g;
                *(f32x4*)(g2q + e*4) = cL2[tl];
            }
        }
        __syncthreads();

        if (t < TT && tid < HH) {
            // layer1 update -> h1[t]
            f32x4 qd = *(const f32x4*)(g1q + tid*4);
            const float x0 = xs[t*3+0], x1 = xs[t*3+1], x2 = xs[t*3+2];
            f32x4 wi = *(const f32x4*)(&w0g[0][tid*4]);
            f32x4 wf = *(const f32x4*)(&w0g[1][tid*4]);
            f32x4 wz = *(const f32x4*)(&w0g[2][tid*4]);
            f32x4 wo = *(const f32x4*)(&w0g[3][tid*4]);
            const float it = qd[0] + wi[0]*x0 + wi[1]*x1 + wi[2]*x2 + wi[3];
            const float ft = qd[1] + wf[0]*x0 + wf[1]*x1 + wf[2]*x2 + wf[3];
            const float zt = qd[2] + wz[0]*x0 + wz[1]*x1 + wz[2]*x2 + wz[3];
            const float ot = qd[3] + wo[0]*x0 + wo[1]*x1 + wo[2]*x2 + wo[3];
            const float mn = fmaxf(ft + m_s, it);
            const float iv = __expf(it - mn);
            const float fv = __expf(ft + m_s - mn);
            const float tq = __expf(-2.f * fabsf(zt));
            float zv = (1.f - tq) * fast_rcp(1.f + tq);
            zv = (zt < 0.f) ? -zv : zv;
            const float ov = fast_rcp(1.f + __expf(-ot));
            c_s = fv * c_s + iv * zv;
            n_s = fv * n_s + iv;
            m_s = mn;
            const float hv = ov * (c_s * fast_rcp(n_s));
            hcat[tid] = (_Float16)hv;
        } else if (t > 0 && tid >= HH && tid < 2*HH) {
            // layer2 update -> h2[t-1]
            const int e = tid - HH;
            f32x4 qd = *(const f32x4*)(g2q + e*4);
            f32x4 bb = *(const f32x4*)(b1qs + e*4);
            const float it = qd[0] + bb[0];
            const float ft = qd[1] + bb[1];
            const float zt = qd[2] + bb[2];
            const float ot = qd[3] + bb[3];
            const float mn = fmaxf(ft + m_s, it);
            const float iv = __expf(it - mn);
            const float fv = __expf(ft + m_s - mn);
            const float tq = __expf(-2.f * fabsf(zt));
            float zv = (1.f - tq) * fast_rcp(1.f + tq);
            zv = (zt < 0.f) ? -zv : zv;
            const float ov = fast_rcp(1.f + __expf(-ot));
            c_s = fv * c_s + iv * zv;
            n_s = fv * n_s + iv;
            m_s = mn;
            const float hv = ov * (c_s * fast_rcp(n_s));
            hlast = hv;
            hcat[HH + e] = (_Float16)hv;
        }
        __syncthreads();
    }

    // ---- output heads ----
    if (tid >= HH && tid < 2*HH) h2f[tid - HH] = hlast;
    __syncthreads();

    if (tid < 2 * NDOUT) {
        const int d = (tid < NDOUT) ? tid : (tid - NDOUT);
        const float* Wr = ((tid < NDOUT) ? Wmu : Wsig) + (size_t)d * HH;
        float acc = (tid < NDOUT) ? bmu[d] : bsig[d];
        #pragma unroll 8
        for (int k = 0; k < HH; ++k) acc += h2f[k] * Wr[k];
        if (tid < NDOUT) {
            out[(size_t)b * NDOUT + d] = acc;
        } else {
            const float sp = fmaxf(acc, 0.f) + log1pf(__expf(-fabsf(acc)));
            out[(size_t)B * NDOUT + (size_t)b * NDOUT + d] = sp + 1e-6f;
        }
    }
}

extern "C" void kernel_launch(void* const* d_in, const int* in_sizes, int n_in,
                              void* d_out, int out_size, void* d_ws, size_t ws_size,
                              hipStream_t stream) {
    const float* x    = (const float*)d_in[0];
    const float* W0   = (const float*)d_in[1];
    const float* R0   = (const float*)d_in[2];
    const float* b0   = (const float*)d_in[3];
    const float* W1   = (const float*)d_in[4];
    const float* R1   = (const float*)d_in[5];
    const float* b1   = (const float*)d_in[6];
    const float* Wmu  = (const float*)d_in[7];
    const float* bmu  = (const float*)d_in[8];
    const float* Wsig = (const float*)d_in[9];
    const float* bsig = (const float*)d_in[10];
    float* out = (float*)d_out;

    const int B = in_sizes[0] / (TT * NDIN);   // 256

    slstm2_mfma<<<B, NTHR, 0, stream>>>(x, W0, R0, b0, W1, R1, b1,
                                        Wmu, bmu, Wsig, bsig, out, B);
}